// Round 7
// baseline (207.993 us; speedup 1.0000x reference)
//
#include <hip/hip_runtime.h>
#include <hip/hip_bf16.h>
#include <stdint.h>

#define NUM_TOKENS 8192
#define HIDDEN 1024
#define NEXP 8
#define TOPK 2

typedef __bf16 bf16;
typedef __bf16 bf16x4 __attribute__((ext_vector_type(4)));
typedef __bf16 bf16x8 __attribute__((ext_vector_type(8)));
typedef float f32x4 __attribute__((ext_vector_type(4)));

// global -> LDS direct copy, 16B per lane. LDS dest must be lane-contiguous.
__device__ __forceinline__ void gld_lds16(const void* g, void* l) {
  __builtin_amdgcn_global_load_lds(
      (const __attribute__((address_space(1))) void*)(uintptr_t)g,
      (__attribute__((address_space(3))) void*)(uint32_t)(uintptr_t)l,
      16, 0, 0);
}

// ---------------------------------------------------------------------------
// Kernel 1 "prep": three independent jobs fused into one launch.
//   blocks [0,2048):    gating (fp32 exact) + x fp32->bf16     (one wave/token)
//   blocks [2048,4096): expert weights fp32->bf16              (16 elem/thread)
//   blocks [4096,6144): zero out                                (16 f32/thread)
// ---------------------------------------------------------------------------
__global__ __launch_bounds__(256) void prep_kernel(
    const float* __restrict__ x, const float* __restrict__ gw,
    const float* __restrict__ ew,
    bf16* __restrict__ xbf, bf16* __restrict__ wbf,
    int* __restrict__ echoice, float* __restrict__ pchoice,
    float* __restrict__ out)
{
  const int b   = blockIdx.x;
  const int tid = threadIdx.x;

  if (b < 2048) {
    // ---- gating + xbf ----
    const int wid  = tid >> 6;
    const int lane = tid & 63;
    const int t = b * 4 + wid;   // t in [0, 8192)

    const float* xrow = x + (size_t)t * HIDDEN;
    bf16* xbrow = xbf + (size_t)t * HIDDEN;

    float acc[NEXP];
#pragma unroll
    for (int e = 0; e < NEXP; ++e) acc[e] = 0.f;

#pragma unroll
    for (int it = 0; it < 4; ++it) {
      const int idx = it * 256 + lane * 4;
      float4 xv = *(const float4*)(xrow + idx);
      bf16x4 xb;
      xb[0] = (bf16)xv.x; xb[1] = (bf16)xv.y; xb[2] = (bf16)xv.z; xb[3] = (bf16)xv.w;
      *(bf16x4*)(xbrow + idx) = xb;
#pragma unroll
      for (int e = 0; e < NEXP; ++e) {
        float4 gv = *(const float4*)(gw + e * HIDDEN + idx);
        acc[e] += xv.x * gv.x + xv.y * gv.y + xv.z * gv.z + xv.w * gv.w;
      }
    }
#pragma unroll
    for (int e = 0; e < NEXP; ++e) {
#pragma unroll
      for (int off = 32; off > 0; off >>= 1)
        acc[e] += __shfl_xor(acc[e], off, 64);
    }

    if (lane == 0) {
      float m = acc[0];
#pragma unroll
      for (int e = 1; e < NEXP; ++e) m = fmaxf(m, acc[e]);
      float p[NEXP]; float s = 0.f;
#pragma unroll
      for (int e = 0; e < NEXP; ++e) { p[e] = expf(acc[e] - m); s += p[e]; }
      const float inv = 1.f / s;
#pragma unroll
      for (int e = 0; e < NEXP; ++e) p[e] *= inv;
      // top-2, ties -> lower index (jax.lax.top_k semantics)
      int i0 = 0; float p0 = p[0];
#pragma unroll
      for (int e = 1; e < NEXP; ++e) if (p[e] > p0) { p0 = p[e]; i0 = e; }
      int i1 = -1; float p1 = -1.f;
#pragma unroll
      for (int e = 0; e < NEXP; ++e) if (e != i0 && p[e] > p1) { p1 = p[e]; i1 = e; }

      echoice[t]              = i0;
      echoice[NUM_TOKENS + t] = i1;
      pchoice[t]              = p0;
      pchoice[NUM_TOKENS + t] = p1;
    }
  } else if (b < 4096) {
    // ---- expert weights fp32 -> bf16, 16 elems/thread ----
    const size_t i = ((size_t)(b - 2048) * 256 + tid) * 16;
    float4 v0 = *(const float4*)(ew + i);
    float4 v1 = *(const float4*)(ew + i + 4);
    float4 v2 = *(const float4*)(ew + i + 8);
    float4 v3 = *(const float4*)(ew + i + 12);
    bf16x8 o0, o1;
    o0[0] = (bf16)v0.x; o0[1] = (bf16)v0.y; o0[2] = (bf16)v0.z; o0[3] = (bf16)v0.w;
    o0[4] = (bf16)v1.x; o0[5] = (bf16)v1.y; o0[6] = (bf16)v1.z; o0[7] = (bf16)v1.w;
    o1[0] = (bf16)v2.x; o1[1] = (bf16)v2.y; o1[2] = (bf16)v2.z; o1[3] = (bf16)v2.w;
    o1[4] = (bf16)v3.x; o1[5] = (bf16)v3.y; o1[6] = (bf16)v3.z; o1[7] = (bf16)v3.w;
    *(bf16x8*)(wbf + i)     = o0;
    *(bf16x8*)(wbf + i + 8) = o1;
  } else {
    // ---- zero out (for the atomic GEMM epilogue), 16 f32/thread ----
    const size_t i = ((size_t)(b - 4096) * 256 + tid) * 16;
    const float4 z = {0.f, 0.f, 0.f, 0.f};
    *(float4*)(out + i)      = z;
    *(float4*)(out + i + 4)  = z;
    *(float4*)(out + i + 8)  = z;
    *(float4*)(out + i + 12) = z;
  }
}

// ---------------------------------------------------------------------------
// Kernel 1b: DETERMINISTIC compaction, 16 blocks (one per (k,expert) list).
// ---------------------------------------------------------------------------
__global__ __launch_bounds__(1024) void build_lists_kernel(
    const int* __restrict__ echoice, const float* __restrict__ pchoice,
    int* __restrict__ cnt, int* __restrict__ tok, float* __restrict__ wt)
{
  const int list = blockIdx.x;         // 0..15
  const int k = list >> 3;
  const int e = list & 7;
  const int tid  = threadIdx.x;
  const int wave = tid >> 6;           // 0..15
  const int lane = tid & 63;
  const int tbase = wave * 512;

  const int*   ec = echoice + k * NUM_TOKENS;
  const float* pc = pchoice + k * NUM_TOKENS;

  __shared__ int wcnt[16];
  __shared__ int woff[16];

  const unsigned long long lower = ((unsigned long long)1 << lane) - 1;

  int   ev[8];
  float pv[8];
#pragma unroll
  for (int c = 0; c < 8; ++c) {
    ev[c] = ec[tbase + c * 64 + lane];
    pv[c] = pc[tbase + c * 64 + lane];
  }
  unsigned long long m[8];
  int cl = 0;
#pragma unroll
  for (int c = 0; c < 8; ++c) { m[c] = __ballot(ev[c] == e); cl += __popcll(m[c]); }
  if (lane == 0) wcnt[wave] = cl;
  __syncthreads();
  if (tid == 0) {
    int off = 0;
#pragma unroll
    for (int w = 0; w < 16; ++w) { woff[w] = off; off += wcnt[w]; }
    cnt[list] = off;
  }
  __syncthreads();
  int run = woff[wave];
#pragma unroll
  for (int c = 0; c < 8; ++c) {
    if (ev[c] == e) {
      const int pos = run + __popcll(m[c] & lower);
      tok[(size_t)list * NUM_TOKENS + pos] = tbase + c * 64 + lane;
      wt [(size_t)list * NUM_TOKENS + pos] = pv[c];
    }
    run += __popcll(m[c]);
  }
}

// ---------------------------------------------------------------------------
// Kernel 1c: build the DENSE tile work queue (round-7 fix). The R6 grid was
// 8192 blocks with only ~1024 useful (mt sized for worst-case counts): useful
// blocks arrived at each CU staggered among empties -> ~2.4 resident useful
// blocks (Occ 30%) -> per-step barrier drains exposed. This queue compacts
// the real tiles and lays them out so slot p holds a tile of expert p%8,
// preserving the FETCH-verified XCD pin (R6: 125MB -> 26MB).
// Entry pack: (list<<9)|(mt<<3)|nt ; -1 = hole (expert imbalance padding).
// Deterministic (pure function of cnt[]).
// ---------------------------------------------------------------------------
__global__ __launch_bounds__(256) void build_work_kernel(
    const int* __restrict__ cnt, int* __restrict__ work, int* __restrict__ nw)
{
  __shared__ int t0s[8], t1s[8];
  const int tid = threadIdx.x;
  if (tid < 8) {
    t0s[tid] = (cnt[tid] + 127) >> 7;       // slot-0 m-tiles of expert tid
    t1s[tid] = (cnt[tid + 8] + 127) >> 7;   // slot-1 m-tiles
  }
  __syncthreads();
  int mx = 0;
#pragma unroll
  for (int e = 0; e < NEXP; ++e) mx = max(mx, (t0s[e] + t1s[e]) * 8);
  if (tid == 0) nw[0] = mx * 8;             // padded total (multiple of 8)
  for (int p = tid; p < mx * 8; p += 256) {
    const int e = p & 7;                    // expert == slot index mod 8
    const int j = p >> 3;                   // item index within expert
    const int tile = j >> 3;
    const int nt = j & 7;
    int w = -1;
    if (tile < t0s[e])              w = (e << 9) | (tile << 3) | nt;
    else if (tile < t0s[e] + t1s[e]) w = ((e + 8) << 9) | ((tile - t0s[e]) << 3) | nt;
    work[p] = w;
  }
}

// ---------------------------------------------------------------------------
// Kernel 2: grouped GEMM, PERSISTENT blocks over the dense work queue.
// Exactly 1024 blocks (4 resident/CU at 33.8KB LDS); block bid grid-strides
// the queue (stride 1024 == 0 mod 8 -> a block always serves expert bid%8 on
// XCD bid%8: its weight panel stays in that XCD's L2 across items).
// Every resident block is useful and arrivals are batched -> one block's
// vmcnt/barrier drain is covered by its 3 co-resident peers (the m97
// mechanism that sustains 56 B/cyc/CU; R6 got 22 at 2.4 loose blocks).
// Inner K-loop / swizzle / epilogue: byte-identical to R6 (4 rounds
// harness-verified, SQ_LDS_BANK_CONFLICT == 0).
// Epilogue: native fp32 atomicAdd into zeroed out; exactly 2 contributions
// per element; fp32 add commutative -> deterministic.
// ---------------------------------------------------------------------------
__global__ __launch_bounds__(256, 4) void moe_gemm_kernel(
    const bf16* __restrict__ xbf, const bf16* __restrict__ wbf,
    const int* __restrict__ cnt, const int* __restrict__ tok,
    const float* __restrict__ wt, const int* __restrict__ work,
    const int* __restrict__ nw, float* __restrict__ out)
{
  __shared__ __align__(16) bf16 As[2][128 * 32];   // 2 x 8KB
  __shared__ __align__(16) bf16 Bs[2][128 * 32];   // 2 x 8KB
  __shared__ int   tok_s[128];
  __shared__ float wt_s[128];

  const int tid = threadIdx.x;
  const int nwork = nw[0];

  const int wid  = tid >> 6;
  const int lane = tid & 63;
  const int wm = (wid >> 1) * 64;
  const int wn = (wid & 1) * 64;
  const int qm = lane & 15;          // m (or n) within 16
  const int l4 = lane >> 4;          // 8-elem k-chunk within 32
  const int csrc = (((tid & 3) ^ ((tid >> 3) & 3)) << 3);  // inverse swizzle, elems
  const int r0 = tid >> 2;                                 // [0,64)

#pragma unroll 1
  for (int idx = blockIdx.x; idx < nwork; idx += 1024) {
    const int w = work[idx];
    if (w < 0) continue;
    const int nt   = w & 7;
    const int mt   = (w >> 3) & 63;
    const int list = (w >> 9) & 15;
    const int e    = list & 7;
    const int count = cnt[list];
    const int m0 = mt * 128;
    const int rows = min(128, count - m0);   // m0 < count by queue construction

    __syncthreads();   // protect tok_s/wt_s from previous item's epilogue readers
    if (tid < 128) {
      if (tid < rows) {
        tok_s[tid] = tok[(size_t)list * NUM_TOKENS + m0 + tid];
        wt_s[tid]  = wt [(size_t)list * NUM_TOKENS + m0 + tid];
      } else { tok_s[tid] = 0; wt_s[tid] = 0.f; }
    }
    __syncthreads();

    // staging: thread -> rows (tid>>2) and (tid>>2)+64, phys chunk tid&3.
    // LDS dest LINEAR (tid*16B; +2048 elems = rows [64,128)). Source carries
    // the inverse swizzle: srcChunk = (tid&3) ^ ((row>>1)&3)  [R3/R4/R6-
    // verified, SQ_LDS_BANK_CONFLICT == 0 on HW].
    const bf16* gA0 = xbf + (size_t)tok_s[r0] * HIDDEN + csrc;
    const bf16* gA1 = xbf + (size_t)tok_s[r0 + 64] * HIDDEN + csrc;
    const bf16* gB0 = wbf + (size_t)e * HIDDEN * HIDDEN
                    + (size_t)(nt * 128 + r0) * HIDDEN + csrc;
    const bf16* gB1 = gB0 + (size_t)64 * HIDDEN;

    auto STAGE = [&](int t, int buf) {
      const int kc = t << 5;
      bf16* la = &As[buf][0] + tid * 8;
      bf16* lb = &Bs[buf][0] + tid * 8;
      gld_lds16(gA0 + kc, la);
      gld_lds16(gA1 + kc, la + 2048);
      gld_lds16(gB0 + kc, lb);
      gld_lds16(gB1 + kc, lb + 2048);
    };

    f32x4 acc[4][4];
#pragma unroll
    for (int i = 0; i < 4; ++i)
#pragma unroll
      for (int j = 0; j < 4; ++j) acc[i][j] = (f32x4){0.f, 0.f, 0.f, 0.f};

    auto COMPUTE = [&](int buf) {
      const bf16* Ab = &As[buf][0];
      const bf16* Bb = &Bs[buf][0];
      bf16x8 a[4], b[4];
#pragma unroll
      for (int i = 0; i < 4; ++i) {
        const int r = wm + i * 16 + qm;
        a[i] = *(const bf16x8*)(Ab + r * 32 + ((l4 ^ ((r >> 1) & 3)) << 3));
      }
#pragma unroll
      for (int j = 0; j < 4; ++j) {
        const int r = wn + j * 16 + qm;
        b[j] = *(const bf16x8*)(Bb + r * 32 + ((l4 ^ ((r >> 1) & 3)) << 3));
      }
      __builtin_amdgcn_s_setprio(1);
#pragma unroll
      for (int i = 0; i < 4; ++i)
#pragma unroll
        for (int j = 0; j < 4; ++j)
          acc[i][j] = __builtin_amdgcn_mfma_f32_16x16x32_bf16(a[i], b[j], acc[i][j], 0, 0, 0);
      __builtin_amdgcn_s_setprio(0);
    };

    // R2/R6-verified loop: stage(t+1) issued BEFORE compute(t); the single
    // end-of-step barrier (compiler drains vmcnt before s_barrier) lands
    // after a full compute phase of latency cover.
    STAGE(0, 0);
    __syncthreads();
#pragma unroll 1
    for (int t = 0; t < 32; ++t) {
      if (t < 31) STAGE(t + 1, (t + 1) & 1);
      COMPUTE(t & 1);
      if (t < 31) __syncthreads();
    }

    // epilogue: C/D layout col=lane&15, row=(lane>>4)*4+reg  (m89-verified)
    const int h0 = nt * 128 + wn + qm;
#pragma unroll
    for (int i = 0; i < 4; ++i) {
      const int rbase = wm + i * 16 + (lane >> 4) * 4;
#pragma unroll
      for (int r = 0; r < 4; ++r) {
        const int rl = rbase + r;
        if (rl < rows) {
          const int t = tok_s[rl];
          const float wgt = wt_s[rl];
          float* orow = out + (size_t)t * HIDDEN + h0;
#pragma unroll
          for (int j = 0; j < 4; ++j) {
            const float v = wgt * acc[i][j][r];
            unsafeAtomicAdd(orow + j * 16, v);   // native global_atomic_add_f32
          }
        }
      }
    }
  }
}

// ---------------------------------------------------------------------------
extern "C" void kernel_launch(void* const* d_in, const int* in_sizes, int n_in,
                              void* d_out, int out_size, void* d_ws, size_t ws_size,
                              hipStream_t stream) {
  const float* x  = (const float*)d_in[0];
  const float* gw = (const float*)d_in[1];
  const float* ew = (const float*)d_in[2];
  float* out = (float*)d_out;

  // ws layout
  char* ws = (char*)d_ws;
  int*   cnt     = (int*)ws;                                           // 16 ints
  int*   nwg     = cnt + 16;                                           // 1 int
  int*   echoice = (int*)(ws + 256);                                   // 2*8192 ints
  float* pchoice = (float*)(ws + 256 + (size_t)2 * NUM_TOKENS * 4);    // 2*8192 f32
  int*   tok = (int*)(ws + 256 + (size_t)4 * NUM_TOKENS * 4);          // 16*8192 ints
  float* wt  = (float*)(ws + 256 + (size_t)20 * NUM_TOKENS * 4);       // 16*8192 f32
  int*   workq = (int*)(ws + 256 + (size_t)36 * NUM_TOKENS * 4);       // 8192 ints (32KB)
  bf16*  xbf = (bf16*)(ws + 256 + (size_t)36 * NUM_TOKENS * 4 + 32768);  // 16MB
  bf16*  wbf = (bf16*)((char*)xbf + (size_t)NUM_TOKENS * HIDDEN * 2);    // 16MB

  prep_kernel<<<6144, 256, 0, stream>>>(x, gw, ew, xbf, wbf, echoice, pchoice, out);
  build_lists_kernel<<<2 * NEXP, 1024, 0, stream>>>(echoice, pchoice, cnt, tok, wt);
  build_work_kernel<<<1, 256, 0, stream>>>(cnt, workq, nwg);

  // 1024 persistent blocks: 4 resident/CU, block bid serves expert bid%8 on
  // XCD bid%8 (queue slot p holds expert p%8; stride 1024 preserves p%8).
  moe_gemm_kernel<<<1024, 256, 0, stream>>>(xbf, wbf, cnt, tok, wt, workq, nwg, out);
}